// Round 5
// baseline (509.619 us; speedup 1.0000x reference)
//
#include <hip/hip_runtime.h>
#include <hip/hip_bf16.h>

// GAT layer, N=8192, DIN=256, DOUT=128.
// h = x@W+bW; e_ij = leaky_relu(s_src[i]+s_dst[j]+ba); p = adj ? exp(e) : 0
// (no max-subtraction: |e| <= ~10 unmasked, fp32-safe). out_i = (sum_j p_ij h_j)/(sum_j p_ij).
//
// R5: split structure. R4 showed the fused phase-A is VGPR-starved (64 VGPRs ->
// ~8 outstanding 16B loads/wave -> measured 830 GB/s, matching the MLP model).
// build_mask instead gets memory-level parallelism from 8.4M independent
// threads (memcpy-like, ~6 TB/s), and writes the 1-bit mask PERMUTED so each
// gat_attn lane's whole mask slice is 32 contiguous bytes = 2 uint4 loads.
// gat_attn's loop then touches only L2-resident data (hbT 2MB, mask 8KB/block,
// s_dst 32KB) -> no HBM latency on any in-loop vmcnt drain.

#define NN 8192
#define DIN 256
#define DOUT 128
#define LOG2E 1.4426950408889634f

typedef __attribute__((ext_vector_type(8))) short short8;   // 8 bf16 = 4 VGPRs (MFMA A/B frag)
typedef __attribute__((ext_vector_type(4))) float floatx4;  // MFMA C/D frag

// ---------------- kernel 0: W [256][128] fp32 -> WT [128][256] bf16 ----------------
__global__ void prep_wt(const float* __restrict__ W, __hip_bfloat16* __restrict__ WT) {
    int e = blockIdx.x * blockDim.x + threadIdx.x;
    if (e < DIN * DOUT) {
        int k = e >> 7;
        int d = e & 127;
        WT[d * DIN + k] = __float2bfloat16(W[e]);
    }
}

// ---------------- kernel 1: h = x@W + bW (MFMA), fused s_src/s_dst (pre-scaled by log2e) ----------------
__global__ __launch_bounds__(256, 4) void gat_h(
    const float* __restrict__ x, const __hip_bfloat16* __restrict__ WT,
    const float* __restrict__ bW, const float* __restrict__ a1, const float* __restrict__ a2,
    __hip_bfloat16* __restrict__ hbT, float* __restrict__ s_src, float* __restrict__ s_dst) {
    int tid = threadIdx.x;
    int w = tid >> 6, lane = tid & 63;
    int lm = lane & 15, lq = lane >> 4;
    int i0 = blockIdx.x * 32;
    int r0 = (w >> 1) * 16;
    int c0 = (w & 1) * 64;

    __shared__ float s1s[32], s2s[32];
    if (tid < 32) { s1s[tid] = 0.f; s2s[tid] = 0.f; }
    __syncthreads();

    floatx4 acc[4] = {};
#pragma unroll
    for (int kk = 0; kk < DIN; kk += 32) {
        const float4* xp = (const float4*)&x[(size_t)(i0 + r0 + lm) * DIN + kk + lq * 8];
        float4 xa = xp[0], xb = xp[1];
        union { short8 v; __hip_bfloat16 h[8]; } af;
        af.h[0] = __float2bfloat16(xa.x); af.h[1] = __float2bfloat16(xa.y);
        af.h[2] = __float2bfloat16(xa.z); af.h[3] = __float2bfloat16(xa.w);
        af.h[4] = __float2bfloat16(xb.x); af.h[5] = __float2bfloat16(xb.y);
        af.h[6] = __float2bfloat16(xb.z); af.h[7] = __float2bfloat16(xb.w);
#pragma unroll
        for (int t = 0; t < 4; t++) {
            int d = c0 + 16 * t + lm;
            short8 bf = *(const short8*)&WT[(size_t)d * DIN + kk + lq * 8];
            acc[t] = __builtin_amdgcn_mfma_f32_16x16x32_bf16(af.v, bf, acc[t], 0, 0, 0);
        }
    }
    float s1[4] = {0.f, 0.f, 0.f, 0.f}, s2[4] = {0.f, 0.f, 0.f, 0.f};
#pragma unroll
    for (int t = 0; t < 4; t++) {
        int d = c0 + 16 * t + lm;
        float A1 = a1[d], A2 = a2[d], B = bW[d];
#pragma unroll
        for (int r = 0; r < 4; r++) {
            int row = r0 + lq * 4 + r;
            float h = acc[t][r] + B;
            hbT[(size_t)d * NN + i0 + row] = __float2bfloat16(h);
            s1[r] += h * A1;
            s2[r] += h * A2;
        }
    }
#pragma unroll
    for (int r = 0; r < 4; r++) {
        for (int m = 1; m < 16; m <<= 1) {
            s1[r] += __shfl_xor(s1[r], m, 64);
            s2[r] += __shfl_xor(s2[r], m, 64);
        }
    }
    if (lm == 0) {
#pragma unroll
        for (int r = 0; r < 4; r++) {
            int row = r0 + lq * 4 + r;
            atomicAdd(&s1s[row], s1[r]);
            atomicAdd(&s2s[row], s2[r]);
        }
    }
    __syncthreads();
    if (tid < 32) {
        s_src[i0 + tid] = s1s[tid] * LOG2E;   // pre-scale: exp(e) = exp2(e*log2e)
        s_dst[i0 + tid] = s2s[tid] * LOG2E;
    }
}

// ---------------- kernel 2: adj -> 1-bit mask, lane-permuted layout ----------------
// Byte-group g (j = g*8..g*8+7) of row r is stored at
//   r*1024 + (g & ~(NJT*4-1)) + (g&3)*NJT + ((g & (NJT*4-1)) >> 2)
// so that gat_attn lane (lm,lq) finds its NJT bytes (t=0..NJT-1) CONTIGUOUS.
// Reads stay perfectly coalesced (thread gid reads adj[gid*8..+7], 2x int4).
template <int NJT>
__global__ void build_mask(const int* __restrict__ adj, unsigned char* __restrict__ mask) {
    size_t gid = (size_t)blockIdx.x * blockDim.x + threadIdx.x;  // 8,388,608 threads
    const int4* a = (const int4*)(adj + gid * 8);
    int4 v0 = a[0], v1 = a[1];
    unsigned int b = 0;
    b |= (v0.x != 0) ? 1u : 0u;
    b |= (v0.y != 0) ? 2u : 0u;
    b |= (v0.z != 0) ? 4u : 0u;
    b |= (v0.w != 0) ? 8u : 0u;
    b |= (v1.x != 0) ? 16u : 0u;
    b |= (v1.y != 0) ? 32u : 0u;
    b |= (v1.z != 0) ? 64u : 0u;
    b |= (v1.w != 0) ? 128u : 0u;
    unsigned int g = (unsigned int)gid & (NJT * 4 - 1);          // within j-split chunk
    size_t pos = (gid & ~(size_t)(NJT * 4 - 1)) | ((g & 3) * NJT + (g >> 2));
    mask[pos] = (unsigned char)b;
}

// ---------------- kernel 3: masked softmax-weighted GEMM, all-cache loop ----------------
// grid = 128 row-blocks x JSPLIT. 4 waves; wave w owns rows ib*64+w*16 and all 128 dims.
template <int NJT>
__global__ __launch_bounds__(256, 4) void gat_attn(
    const unsigned char* __restrict__ mask, const float* __restrict__ s_src,
    const float* __restrict__ s_dst, const float* __restrict__ ba_p,
    const __hip_bfloat16* __restrict__ hbT,
    float* __restrict__ num, float* __restrict__ lpart) {
    int tid = threadIdx.x;
    int w = tid >> 6, lane = tid & 63;
    int lm = lane & 15, lq = lane >> 4;
    int b = blockIdx.x;
    int ib = b & 127;
    int jh = b >> 7;
    int i0 = ib * 64 + w * 16;
    int jb0 = jh * (NJT * 32);

    // phase A: this lane's whole mask slice = NJT contiguous bytes
    const unsigned char* mrow = mask + (size_t)(i0 + lm) * (NN / 8) + jh * (NJT * 4) + lq * NJT;
    union { uint4 v[NJT / 16]; unsigned int u[NJT / 4]; } mr;
#pragma unroll
    for (int q = 0; q < NJT / 16; q++) mr.v[q] = ((const uint4*)mrow)[q];

    float ssi = s_src[i0 + lm] + ba_p[0] * LOG2E;
    const float* sd = s_dst + jb0 + lq * 8;
    const __hip_bfloat16* hbb = hbT + (size_t)lm * NN + jb0 + lq * 8;

    floatx4 acc[8] = {};
    floatx4 accd = {};
    const short8 ones = { 0x3F80, 0x3F80, 0x3F80, 0x3F80, 0x3F80, 0x3F80, 0x3F80, 0x3F80 };

#pragma unroll
    for (int t = 0; t < NJT; t++) {
        unsigned int cm = (mr.u[t >> 2] >> ((t & 3) * 8)) & 0xFFu;
        float4 cd0 = *(const float4*)(sd + t * 32);
        float4 cd1 = *(const float4*)(sd + t * 32 + 4);
        float p[8];
        {
            float e;
            e = ssi + cd0.x; e = fmaxf(e, 0.01f * e); p[0] = (cm & 1u)   ? __builtin_amdgcn_exp2f(e) : 0.f;
            e = ssi + cd0.y; e = fmaxf(e, 0.01f * e); p[1] = (cm & 2u)   ? __builtin_amdgcn_exp2f(e) : 0.f;
            e = ssi + cd0.z; e = fmaxf(e, 0.01f * e); p[2] = (cm & 4u)   ? __builtin_amdgcn_exp2f(e) : 0.f;
            e = ssi + cd0.w; e = fmaxf(e, 0.01f * e); p[3] = (cm & 8u)   ? __builtin_amdgcn_exp2f(e) : 0.f;
            e = ssi + cd1.x; e = fmaxf(e, 0.01f * e); p[4] = (cm & 16u)  ? __builtin_amdgcn_exp2f(e) : 0.f;
            e = ssi + cd1.y; e = fmaxf(e, 0.01f * e); p[5] = (cm & 32u)  ? __builtin_amdgcn_exp2f(e) : 0.f;
            e = ssi + cd1.z; e = fmaxf(e, 0.01f * e); p[6] = (cm & 64u)  ? __builtin_amdgcn_exp2f(e) : 0.f;
            e = ssi + cd1.w; e = fmaxf(e, 0.01f * e); p[7] = (cm & 128u) ? __builtin_amdgcn_exp2f(e) : 0.f;
        }
        union { short8 v; __hip_bfloat162 q[4]; } af;
        af.q[0] = __float22bfloat162_rn(make_float2(p[0], p[1]));
        af.q[1] = __float22bfloat162_rn(make_float2(p[2], p[3]));
        af.q[2] = __float22bfloat162_rn(make_float2(p[4], p[5]));
        af.q[3] = __float22bfloat162_rn(make_float2(p[6], p[7]));

        size_t off = (size_t)t * 32;
#pragma unroll
        for (int f = 0; f < 8; f++) {
            short8 bf = *(const short8*)(hbb + (size_t)f * 16 * NN + off);
            acc[f] = __builtin_amdgcn_mfma_f32_16x16x32_bf16(af.v, bf, acc[f], 0, 0, 0);
        }
        accd = __builtin_amdgcn_mfma_f32_16x16x32_bf16(af.v, ones, accd, 0, 0, 0);
    }

    // epilogue: C/D layout col=lm, row=lq*4+r
    float* nb = num + ((size_t)jh * NN + i0) * DOUT;
#pragma unroll
    for (int f = 0; f < 8; f++)
#pragma unroll
        for (int r = 0; r < 4; r++)
            nb[(size_t)(lq * 4 + r) * DOUT + f * 16 + lm] = acc[f][r];
    if (lm == 0) {
#pragma unroll
        for (int r = 0; r < 4; r++)
            lpart[(size_t)jh * NN + i0 + lq * 4 + r] = accd[r];
    }
}

// ---------------- kernel 4: combine partials, divide ----------------
__global__ void gat_combine(const float* __restrict__ num, const float* __restrict__ lpart,
                            float* __restrict__ out, int jsplit) {
    int gid = blockIdx.x * blockDim.x + threadIdx.x;  // 262144 threads, one float4 each
    int idx = gid * 4;
    int i = idx >> 7;
    float den = 0.f;
    for (int s = 0; s < jsplit; s++) den += lpart[(size_t)s * NN + i];
    float inv = 1.0f / den;
    float4 o = make_float4(0.f, 0.f, 0.f, 0.f);
    for (int s = 0; s < jsplit; s++) {
        float4 n = *(const float4*)&num[(size_t)s * NN * DOUT + idx];
        o.x += n.x; o.y += n.y; o.z += n.z; o.w += n.w;
    }
    o.x *= inv; o.y *= inv; o.z *= inv; o.w *= inv;
    *(float4*)&out[idx] = o;
}

extern "C" void kernel_launch(void* const* d_in, const int* in_sizes, int n_in,
                              void* d_out, int out_size, void* d_ws, size_t ws_size,
                              hipStream_t stream) {
    const float* x  = (const float*)d_in[0];
    const int* adj  = (const int*)d_in[1];
    const float* W  = (const float*)d_in[2];
    const float* bW = (const float*)d_in[3];
    const float* a1 = (const float*)d_in[4];
    const float* a2 = (const float*)d_in[5];
    const float* ba = (const float*)d_in[6];
    float* out = (float*)d_out;

    char* ws = (char*)d_ws;
    __hip_bfloat16* hbT  = (__hip_bfloat16*)ws;                    // 2 MB   [128][8192]
    __hip_bfloat16* WT   = (__hip_bfloat16*)(ws + 2097152);        // 64 KB
    float* s_src         = (float*)(ws + 2162688);                 // 32 KB (pre-scaled by log2e)
    float* s_dst         = (float*)(ws + 2195456);                 // 32 KB (pre-scaled by log2e)
    float* lpart         = (float*)(ws + 2228224);                 // 256 KB [<=8][8192]
    unsigned char* mask  = (unsigned char*)(ws + 2490368);         // 8 MB   [8192][1024] permuted
    float* num           = (float*)(ws + 10878976);                // jsplit*4 MB

    int jsplit = (ws_size >= 10878976 + (size_t)8 * NN * DOUT * 4) ? 8 : 4;

    prep_wt<<<128, 256, 0, stream>>>(W, WT);
    gat_h<<<256, 256, 0, stream>>>(x, WT, bW, a1, a2, hbT, s_src, s_dst);
    if (jsplit == 8) {
        build_mask<32><<<32768, 256, 0, stream>>>(adj, mask);
        gat_attn<32><<<1024, 256, 0, stream>>>(mask, s_src, s_dst, ba, hbT, num, lpart);
    } else {
        build_mask<64><<<32768, 256, 0, stream>>>(adj, mask);
        gat_attn<64><<<512, 256, 0, stream>>>(mask, s_src, s_dst, ba, hbT, num, lpart);
    }
    gat_combine<<<1024, 256, 0, stream>>>(num, lpart, out, jsplit);
}

// Round 6
// 459.126 us; speedup vs baseline: 1.1100x; 1.1100x over previous
//
#include <hip/hip_runtime.h>
#include <hip/hip_bf16.h>

// GAT layer, N=8192, DIN=256, DOUT=128.
// h = x@W+bW; e_ij = leaky_relu(s_src[i]+s_dst[j]+ba); p = adj ? exp(e) : 0
// (no max-subtraction: |e| <= ~10 unmasked, fp32-safe). out_i = (sum_j p_ij h_j)/(sum_j p_ij).
//
// R6: h is stored in MFMA B-FRAGMENT-TILE order ("hbB"): for j-tile g (32 rows
// of h = 32 j's) and frag f (dims f*16..f*16+15), the wave's B-frag is 64
// lanes x 16B CONTIGUOUS. R5's gat_attn loads had 16-way address divergence
// (lanes strided 16KB -> 16 disjoint 64B segments per load instr, 288 loads,
// L1 thrash + in-order vmcnt serialization ~ the hidden ~160us). Now every
// B-frag load is one sequential 1KB burst.
// hbB flat index for h-element (row i, dim d):
//   g=i>>5, k=i&31, f=d>>4, n=d&15 -> g*4096 + f*512 + (k>>3)*128 + n*8 + (k&7)
// (B-frag lane = 16*(k>>3)+n holds B[k][n], idx k&7 — matches 16x16x32 layout.)

#define NN 8192
#define DIN 256
#define DOUT 128
#define LOG2E 1.4426950408889634f

typedef __attribute__((ext_vector_type(8))) short short8;   // 8 bf16 = 4 VGPRs (MFMA A/B frag)
typedef __attribute__((ext_vector_type(4))) float floatx4;  // MFMA C/D frag

// ---------------- kernel 0: W [256][128] fp32 -> WT [128][256] bf16 ----------------
__global__ void prep_wt(const float* __restrict__ W, __hip_bfloat16* __restrict__ WT) {
    int e = blockIdx.x * blockDim.x + threadIdx.x;
    if (e < DIN * DOUT) {
        int k = e >> 7;
        int d = e & 127;
        WT[d * DIN + k] = __float2bfloat16(W[e]);
    }
}

// ---------------- kernel 1: h = x@W + bW (MFMA), fused s_src/s_dst; h -> hbB frag-tile layout ----------------
__global__ __launch_bounds__(256, 4) void gat_h(
    const float* __restrict__ x, const __hip_bfloat16* __restrict__ WT,
    const float* __restrict__ bW, const float* __restrict__ a1, const float* __restrict__ a2,
    __hip_bfloat16* __restrict__ hbB, float* __restrict__ s_src, float* __restrict__ s_dst) {
    int tid = threadIdx.x;
    int w = tid >> 6, lane = tid & 63;
    int lm = lane & 15, lq = lane >> 4;
    int i0 = blockIdx.x * 32;
    int r0 = (w >> 1) * 16;
    int c0 = (w & 1) * 64;

    __shared__ float s1s[32], s2s[32];
    if (tid < 32) { s1s[tid] = 0.f; s2s[tid] = 0.f; }
    __syncthreads();

    floatx4 acc[4] = {};
#pragma unroll
    for (int kk = 0; kk < DIN; kk += 32) {
        const float4* xp = (const float4*)&x[(size_t)(i0 + r0 + lm) * DIN + kk + lq * 8];
        float4 xa = xp[0], xb = xp[1];
        union { short8 v; __hip_bfloat16 h[8]; } af;
        af.h[0] = __float2bfloat16(xa.x); af.h[1] = __float2bfloat16(xa.y);
        af.h[2] = __float2bfloat16(xa.z); af.h[3] = __float2bfloat16(xa.w);
        af.h[4] = __float2bfloat16(xb.x); af.h[5] = __float2bfloat16(xb.y);
        af.h[6] = __float2bfloat16(xb.z); af.h[7] = __float2bfloat16(xb.w);
#pragma unroll
        for (int t = 0; t < 4; t++) {
            int d = c0 + 16 * t + lm;
            short8 bf = *(const short8*)&WT[(size_t)d * DIN + kk + lq * 8];
            acc[t] = __builtin_amdgcn_mfma_f32_16x16x32_bf16(af.v, bf, acc[t], 0, 0, 0);
        }
    }
    float s1[4] = {0.f, 0.f, 0.f, 0.f}, s2[4] = {0.f, 0.f, 0.f, 0.f};
    // hbB: g = blockIdx.x (all 32 rows of this block are one j-tile), k = r0+lq*4+r
#pragma unroll
    for (int t = 0; t < 4; t++) {
        int d = c0 + 16 * t + lm;
        int f = (c0 >> 4) + t;
        float A1 = a1[d], A2 = a2[d], B = bW[d];
#pragma unroll
        for (int r = 0; r < 4; r++) {
            int k = r0 + lq * 4 + r;
            float h = acc[t][r] + B;
            hbB[(size_t)blockIdx.x * 4096 + f * 512 + (k >> 3) * 128 + lm * 8 + (k & 7)] =
                __float2bfloat16(h);
            s1[r] += h * A1;
            s2[r] += h * A2;
        }
    }
#pragma unroll
    for (int r = 0; r < 4; r++) {
        for (int m = 1; m < 16; m <<= 1) {
            s1[r] += __shfl_xor(s1[r], m, 64);
            s2[r] += __shfl_xor(s2[r], m, 64);
        }
    }
    if (lm == 0) {
#pragma unroll
        for (int r = 0; r < 4; r++) {
            int row = r0 + lq * 4 + r;
            atomicAdd(&s1s[row], s1[r]);
            atomicAdd(&s2s[row], s2[r]);
        }
    }
    __syncthreads();
    if (tid < 32) {
        s_src[i0 + tid] = s1s[tid] * LOG2E;   // pre-scale: exp(e) = exp2(e*log2e)
        s_dst[i0 + tid] = s2s[tid] * LOG2E;
    }
}

// ---------------- kernel 2: adj -> 1-bit mask, lane-permuted layout ----------------
template <int NJT>
__global__ void build_mask(const int* __restrict__ adj, unsigned char* __restrict__ mask) {
    size_t gid = (size_t)blockIdx.x * blockDim.x + threadIdx.x;  // 8,388,608 threads
    const int4* a = (const int4*)(adj + gid * 8);
    int4 v0 = a[0], v1 = a[1];
    unsigned int b = 0;
    b |= (v0.x != 0) ? 1u : 0u;
    b |= (v0.y != 0) ? 2u : 0u;
    b |= (v0.z != 0) ? 4u : 0u;
    b |= (v0.w != 0) ? 8u : 0u;
    b |= (v1.x != 0) ? 16u : 0u;
    b |= (v1.y != 0) ? 32u : 0u;
    b |= (v1.z != 0) ? 64u : 0u;
    b |= (v1.w != 0) ? 128u : 0u;
    unsigned int g = (unsigned int)gid & (NJT * 4 - 1);
    size_t pos = (gid & ~(size_t)(NJT * 4 - 1)) | ((g & 3) * NJT + (g >> 2));
    mask[pos] = (unsigned char)b;
}

// ---------------- kernel 3: masked softmax-weighted GEMM, contiguous B-frags ----------------
// grid = 128 row-blocks x JSPLIT. 4 waves; wave w owns rows ib*64+w*16 and all 128 dims.
template <int NJT>
__global__ __launch_bounds__(256, 4) void gat_attn(
    const unsigned char* __restrict__ mask, const float* __restrict__ s_src,
    const float* __restrict__ s_dst, const float* __restrict__ ba_p,
    const __hip_bfloat16* __restrict__ hbB,
    float* __restrict__ num, float* __restrict__ lpart) {
    int tid = threadIdx.x;
    int w = tid >> 6, lane = tid & 63;
    int lm = lane & 15, lq = lane >> 4;
    int b = blockIdx.x;
    int ib = b & 127;
    int jh = b >> 7;
    int i0 = ib * 64 + w * 16;
    int jb0 = jh * (NJT * 32);

    // phase A: this lane's whole mask slice = NJT contiguous bytes
    const unsigned char* mrow = mask + (size_t)(i0 + lm) * (NN / 8) + jh * (NJT * 4) + lq * NJT;
    union { uint4 v[NJT / 16]; unsigned int u[NJT / 4]; } mr;
#pragma unroll
    for (int q = 0; q < NJT / 16; q++) mr.v[q] = ((const uint4*)mrow)[q];

    float ssi = s_src[i0 + lm] + ba_p[0] * LOG2E;
    const float* sd = s_dst + jb0 + lq * 8;
    // B-frag base: tile g = jh*NJT + t, frag f, lane -> one contiguous 1KB per frag
    const __hip_bfloat16* hb = hbB + ((size_t)(jh * NJT) * 8) * 512 + lane * 8;

    floatx4 acc[8] = {};
    floatx4 accd = {};
    const short8 ones = { 0x3F80, 0x3F80, 0x3F80, 0x3F80, 0x3F80, 0x3F80, 0x3F80, 0x3F80 };

#pragma unroll
    for (int t = 0; t < NJT; t++) {
        unsigned int cm = (mr.u[t >> 2] >> ((t & 3) * 8)) & 0xFFu;
        float4 cd0 = *(const float4*)(sd + t * 32);
        float4 cd1 = *(const float4*)(sd + t * 32 + 4);
        float p[8];
        {
            float e;
            e = ssi + cd0.x; e = fmaxf(e, 0.01f * e); p[0] = (cm & 1u)   ? __builtin_amdgcn_exp2f(e) : 0.f;
            e = ssi + cd0.y; e = fmaxf(e, 0.01f * e); p[1] = (cm & 2u)   ? __builtin_amdgcn_exp2f(e) : 0.f;
            e = ssi + cd0.z; e = fmaxf(e, 0.01f * e); p[2] = (cm & 4u)   ? __builtin_amdgcn_exp2f(e) : 0.f;
            e = ssi + cd0.w; e = fmaxf(e, 0.01f * e); p[3] = (cm & 8u)   ? __builtin_amdgcn_exp2f(e) : 0.f;
            e = ssi + cd1.x; e = fmaxf(e, 0.01f * e); p[4] = (cm & 16u)  ? __builtin_amdgcn_exp2f(e) : 0.f;
            e = ssi + cd1.y; e = fmaxf(e, 0.01f * e); p[5] = (cm & 32u)  ? __builtin_amdgcn_exp2f(e) : 0.f;
            e = ssi + cd1.z; e = fmaxf(e, 0.01f * e); p[6] = (cm & 64u)  ? __builtin_amdgcn_exp2f(e) : 0.f;
            e = ssi + cd1.w; e = fmaxf(e, 0.01f * e); p[7] = (cm & 128u) ? __builtin_amdgcn_exp2f(e) : 0.f;
        }
        union { short8 v; __hip_bfloat162 q[4]; } af;
        af.q[0] = __float22bfloat162_rn(make_float2(p[0], p[1]));
        af.q[1] = __float22bfloat162_rn(make_float2(p[2], p[3]));
        af.q[2] = __float22bfloat162_rn(make_float2(p[4], p[5]));
        af.q[3] = __float22bfloat162_rn(make_float2(p[6], p[7]));

        const __hip_bfloat16* hbt = hb + (size_t)t * 8 * 512;
#pragma unroll
        for (int f = 0; f < 8; f++) {
            short8 bf = *(const short8*)(hbt + f * 512);
            acc[f] = __builtin_amdgcn_mfma_f32_16x16x32_bf16(af.v, bf, acc[f], 0, 0, 0);
        }
        accd = __builtin_amdgcn_mfma_f32_16x16x32_bf16(af.v, ones, accd, 0, 0, 0);
    }

    // epilogue: C/D layout col=lm, row=lq*4+r
    float* nb = num + ((size_t)jh * NN + i0) * DOUT;
#pragma unroll
    for (int f = 0; f < 8; f++)
#pragma unroll
        for (int r = 0; r < 4; r++)
            nb[(size_t)(lq * 4 + r) * DOUT + f * 16 + lm] = acc[f][r];
    if (lm == 0) {
#pragma unroll
        for (int r = 0; r < 4; r++)
            lpart[(size_t)jh * NN + i0 + lq * 4 + r] = accd[r];
    }
}

// ---------------- kernel 4: combine partials, divide ----------------
__global__ void gat_combine(const float* __restrict__ num, const float* __restrict__ lpart,
                            float* __restrict__ out, int jsplit) {
    int gid = blockIdx.x * blockDim.x + threadIdx.x;  // 262144 threads, one float4 each
    int idx = gid * 4;
    int i = idx >> 7;
    float den = 0.f;
    for (int s = 0; s < jsplit; s++) den += lpart[(size_t)s * NN + i];
    float inv = 1.0f / den;
    float4 o = make_float4(0.f, 0.f, 0.f, 0.f);
    for (int s = 0; s < jsplit; s++) {
        float4 n = *(const float4*)&num[(size_t)s * NN * DOUT + idx];
        o.x += n.x; o.y += n.y; o.z += n.z; o.w += n.w;
    }
    o.x *= inv; o.y *= inv; o.z *= inv; o.w *= inv;
    *(float4*)&out[idx] = o;
}

extern "C" void kernel_launch(void* const* d_in, const int* in_sizes, int n_in,
                              void* d_out, int out_size, void* d_ws, size_t ws_size,
                              hipStream_t stream) {
    const float* x  = (const float*)d_in[0];
    const int* adj  = (const int*)d_in[1];
    const float* W  = (const float*)d_in[2];
    const float* bW = (const float*)d_in[3];
    const float* a1 = (const float*)d_in[4];
    const float* a2 = (const float*)d_in[5];
    const float* ba = (const float*)d_in[6];
    float* out = (float*)d_out;

    char* ws = (char*)d_ws;
    __hip_bfloat16* hbB  = (__hip_bfloat16*)ws;                    // 2 MB   frag-tile layout
    __hip_bfloat16* WT   = (__hip_bfloat16*)(ws + 2097152);        // 64 KB
    float* s_src         = (float*)(ws + 2162688);                 // 32 KB (pre-scaled by log2e)
    float* s_dst         = (float*)(ws + 2195456);                 // 32 KB (pre-scaled by log2e)
    float* lpart         = (float*)(ws + 2228224);                 // 256 KB [<=8][8192]
    unsigned char* mask  = (unsigned char*)(ws + 2490368);         // 8 MB   permuted
    float* num           = (float*)(ws + 10878976);                // jsplit*4 MB

    int jsplit = (ws_size >= 10878976 + (size_t)8 * NN * DOUT * 4) ? 8 : 4;

    prep_wt<<<128, 256, 0, stream>>>(W, WT);
    gat_h<<<256, 256, 0, stream>>>(x, WT, bW, a1, a2, hbB, s_src, s_dst);
    if (jsplit == 8) {
        build_mask<32><<<32768, 256, 0, stream>>>(adj, mask);
        gat_attn<32><<<1024, 256, 0, stream>>>(mask, s_src, s_dst, ba, hbB, num, lpart);
    } else {
        build_mask<64><<<32768, 256, 0, stream>>>(adj, mask);
        gat_attn<64><<<512, 256, 0, stream>>>(mask, s_src, s_dst, ba, hbB, num, lpart);
    }
    gat_combine<<<1024, 256, 0, stream>>>(num, lpart, out, jsplit);
}

// Round 7
// 437.269 us; speedup vs baseline: 1.1655x; 1.0500x over previous
//
#include <hip/hip_runtime.h>
#include <hip/hip_bf16.h>

// GAT layer, N=8192, DIN=256, DOUT=128.
// h = x@W+bW; e_ij = leaky_relu(s_src[i]+s_dst[j]+ba); p = adj ? exp(e) : 0
// (no max-subtraction: |e| <= ~10 unmasked, fp32-safe). out_i = (sum_j p_ij h_j)/(sum_j p_ij).
//
// R7: 32 rows per wave (two A-frags share every B-frag). Total B-frag L2
// traffic scales 1/I: I=16 -> 1.07 GB (~31us at L2 BW), I=32 -> 536 MB.
// R6 accounting put gat_attn at ~125us with VALU ~25 / MFMA ~8 / L2 ~31 --
// B-reuse is the dominant reducible term. jsplit=16 keeps grid=1024 (>=3
// blocks/CU at launch_bounds(256,3)). build_mask runs FIRST so the 268 MB
// adj stream doesn't evict gat_h's outputs from L2 before gat_attn.

#define NN 8192
#define DIN 256
#define DOUT 128
#define LOG2E 1.4426950408889634f

typedef __attribute__((ext_vector_type(8))) short short8;   // 8 bf16 = 4 VGPRs (MFMA A/B frag)
typedef __attribute__((ext_vector_type(4))) float floatx4;  // MFMA C/D frag

// ---------------- kernel 0: W [256][128] fp32 -> WT [128][256] bf16 ----------------
__global__ void prep_wt(const float* __restrict__ W, __hip_bfloat16* __restrict__ WT) {
    int e = blockIdx.x * blockDim.x + threadIdx.x;
    if (e < DIN * DOUT) {
        int k = e >> 7;
        int d = e & 127;
        WT[d * DIN + k] = __float2bfloat16(W[e]);
    }
}

// ---------------- kernel 1: h = x@W + bW (MFMA), fused s_src/s_dst; h -> hbB frag-tile layout ----------------
// hbB flat index for h-element (row i, dim d):
//   g=i>>5, k=i&31, f=d>>4, n=d&15 -> g*4096 + f*512 + (k>>3)*128 + n*8 + (k&7)
__global__ __launch_bounds__(256, 4) void gat_h(
    const float* __restrict__ x, const __hip_bfloat16* __restrict__ WT,
    const float* __restrict__ bW, const float* __restrict__ a1, const float* __restrict__ a2,
    __hip_bfloat16* __restrict__ hbB, float* __restrict__ s_src, float* __restrict__ s_dst) {
    int tid = threadIdx.x;
    int w = tid >> 6, lane = tid & 63;
    int lm = lane & 15, lq = lane >> 4;
    int i0 = blockIdx.x * 32;
    int r0 = (w >> 1) * 16;
    int c0 = (w & 1) * 64;

    __shared__ float s1s[32], s2s[32];
    if (tid < 32) { s1s[tid] = 0.f; s2s[tid] = 0.f; }
    __syncthreads();

    floatx4 acc[4] = {};
#pragma unroll
    for (int kk = 0; kk < DIN; kk += 32) {
        const float4* xp = (const float4*)&x[(size_t)(i0 + r0 + lm) * DIN + kk + lq * 8];
        float4 xa = xp[0], xb = xp[1];
        union { short8 v; __hip_bfloat16 h[8]; } af;
        af.h[0] = __float2bfloat16(xa.x); af.h[1] = __float2bfloat16(xa.y);
        af.h[2] = __float2bfloat16(xa.z); af.h[3] = __float2bfloat16(xa.w);
        af.h[4] = __float2bfloat16(xb.x); af.h[5] = __float2bfloat16(xb.y);
        af.h[6] = __float2bfloat16(xb.z); af.h[7] = __float2bfloat16(xb.w);
#pragma unroll
        for (int t = 0; t < 4; t++) {
            int d = c0 + 16 * t + lm;
            short8 bf = *(const short8*)&WT[(size_t)d * DIN + kk + lq * 8];
            acc[t] = __builtin_amdgcn_mfma_f32_16x16x32_bf16(af.v, bf, acc[t], 0, 0, 0);
        }
    }
    float s1[4] = {0.f, 0.f, 0.f, 0.f}, s2[4] = {0.f, 0.f, 0.f, 0.f};
#pragma unroll
    for (int t = 0; t < 4; t++) {
        int d = c0 + 16 * t + lm;
        int f = (c0 >> 4) + t;
        float A1 = a1[d], A2 = a2[d], B = bW[d];
#pragma unroll
        for (int r = 0; r < 4; r++) {
            int k = r0 + lq * 4 + r;
            float h = acc[t][r] + B;
            hbB[(size_t)blockIdx.x * 4096 + f * 512 + (k >> 3) * 128 + lm * 8 + (k & 7)] =
                __float2bfloat16(h);
            s1[r] += h * A1;
            s2[r] += h * A2;
        }
    }
#pragma unroll
    for (int r = 0; r < 4; r++) {
        for (int m = 1; m < 16; m <<= 1) {
            s1[r] += __shfl_xor(s1[r], m, 64);
            s2[r] += __shfl_xor(s2[r], m, 64);
        }
    }
    if (lm == 0) {
#pragma unroll
        for (int r = 0; r < 4; r++) {
            int row = r0 + lq * 4 + r;
            atomicAdd(&s1s[row], s1[r]);
            atomicAdd(&s2s[row], s2[r]);
        }
    }
    __syncthreads();
    if (tid < 32) {
        s_src[i0 + tid] = s1s[tid] * LOG2E;   // pre-scale: exp(e) = exp2(e*log2e)
        s_dst[i0 + tid] = s2s[tid] * LOG2E;
    }
}

// ---------------- kernel 2: adj -> 1-bit mask, lane-permuted layout ----------------
// byte-group g of row r stored so gat_attn lane's NJT bytes are contiguous.
template <int NJT>
__global__ void build_mask(const int* __restrict__ adj, unsigned char* __restrict__ mask) {
    size_t gid = (size_t)blockIdx.x * blockDim.x + threadIdx.x;  // 8,388,608 threads
    const int4* a = (const int4*)(adj + gid * 8);
    int4 v0 = a[0], v1 = a[1];
    unsigned int b = 0;
    b |= (v0.x != 0) ? 1u : 0u;
    b |= (v0.y != 0) ? 2u : 0u;
    b |= (v0.z != 0) ? 4u : 0u;
    b |= (v0.w != 0) ? 8u : 0u;
    b |= (v1.x != 0) ? 16u : 0u;
    b |= (v1.y != 0) ? 32u : 0u;
    b |= (v1.z != 0) ? 64u : 0u;
    b |= (v1.w != 0) ? 128u : 0u;
    unsigned int g = (unsigned int)gid & (NJT * 4 - 1);
    size_t pos = (gid & ~(size_t)(NJT * 4 - 1)) | ((g & 3) * NJT + (g >> 2));
    mask[pos] = (unsigned char)b;
}

__device__ inline short8 make_pfrag(unsigned int cm, float ssi, float4 cd0, float4 cd1,
                                    floatx4* accd, const short8 ones) {
    float p[8];
    float e;
    e = ssi + cd0.x; e = fmaxf(e, 0.01f * e); p[0] = (cm & 1u)   ? __builtin_amdgcn_exp2f(e) : 0.f;
    e = ssi + cd0.y; e = fmaxf(e, 0.01f * e); p[1] = (cm & 2u)   ? __builtin_amdgcn_exp2f(e) : 0.f;
    e = ssi + cd0.z; e = fmaxf(e, 0.01f * e); p[2] = (cm & 4u)   ? __builtin_amdgcn_exp2f(e) : 0.f;
    e = ssi + cd0.w; e = fmaxf(e, 0.01f * e); p[3] = (cm & 8u)   ? __builtin_amdgcn_exp2f(e) : 0.f;
    e = ssi + cd1.x; e = fmaxf(e, 0.01f * e); p[4] = (cm & 16u)  ? __builtin_amdgcn_exp2f(e) : 0.f;
    e = ssi + cd1.y; e = fmaxf(e, 0.01f * e); p[5] = (cm & 32u)  ? __builtin_amdgcn_exp2f(e) : 0.f;
    e = ssi + cd1.z; e = fmaxf(e, 0.01f * e); p[6] = (cm & 64u)  ? __builtin_amdgcn_exp2f(e) : 0.f;
    e = ssi + cd1.w; e = fmaxf(e, 0.01f * e); p[7] = (cm & 128u) ? __builtin_amdgcn_exp2f(e) : 0.f;
    union { short8 v; __hip_bfloat162 q[4]; } af;
    af.q[0] = __float22bfloat162_rn(make_float2(p[0], p[1]));
    af.q[1] = __float22bfloat162_rn(make_float2(p[2], p[3]));
    af.q[2] = __float22bfloat162_rn(make_float2(p[4], p[5]));
    af.q[3] = __float22bfloat162_rn(make_float2(p[6], p[7]));
    *accd = __builtin_amdgcn_mfma_f32_16x16x32_bf16(af.v, ones, *accd, 0, 0, 0);
    return af.v;
}

// ---------------- kernel 3: masked softmax-weighted GEMM, 32 rows/wave ----------------
// grid = 64 row-blocks (128 rows) x JSPLIT. Wave w: rows i0=ib*128+w*32 .. +31
// as two A-frag row-groups sharing each B-frag; all 128 dims.
template <int NJT>
__global__ __launch_bounds__(256, 3) void gat_attn(
    const unsigned char* __restrict__ mask, const float* __restrict__ s_src,
    const float* __restrict__ s_dst, const float* __restrict__ ba_p,
    const __hip_bfloat16* __restrict__ hbB,
    float* __restrict__ num, float* __restrict__ lpart) {
    int tid = threadIdx.x;
    int w = tid >> 6, lane = tid & 63;
    int lm = lane & 15, lq = lane >> 4;
    int b = blockIdx.x;
    int ib = b & 63;
    int jh = b >> 6;
    int i0 = ib * 128 + w * 32;
    int jb0 = jh * (NJT * 32);

    // per-lane mask slices for both row-groups: NJT contiguous bytes each
    const unsigned char* mrow0 = mask + (size_t)(i0 + lm) * (NN / 8) + jh * (NJT * 4) + lq * NJT;
    const unsigned char* mrow1 = mrow0 + (size_t)16 * (NN / 8);
    union Mr { uint4 v[NJT / 16]; unsigned int u[NJT / 4]; };
    Mr mr0, mr1;
#pragma unroll
    for (int q = 0; q < NJT / 16; q++) {
        mr0.v[q] = ((const uint4*)mrow0)[q];
        mr1.v[q] = ((const uint4*)mrow1)[q];
    }

    float ba = ba_p[0] * LOG2E;
    float ssi0 = s_src[i0 + lm] + ba;
    float ssi1 = s_src[i0 + 16 + lm] + ba;
    const float* sd = s_dst + jb0 + lq * 8;
    const __hip_bfloat16* hb = hbB + ((size_t)(jh * NJT) * 8) * 512 + lane * 8;

    floatx4 acc0[8] = {}, acc1[8] = {};
    floatx4 accd0 = {}, accd1 = {};
    const short8 ones = { 0x3F80, 0x3F80, 0x3F80, 0x3F80, 0x3F80, 0x3F80, 0x3F80, 0x3F80 };

#pragma unroll
    for (int t = 0; t < NJT; t++) {
        unsigned int cm0 = (mr0.u[t >> 2] >> ((t & 3) * 8)) & 0xFFu;
        unsigned int cm1 = (mr1.u[t >> 2] >> ((t & 3) * 8)) & 0xFFu;
        float4 cd0 = *(const float4*)(sd + t * 32);
        float4 cd1 = *(const float4*)(sd + t * 32 + 4);
        short8 af0 = make_pfrag(cm0, ssi0, cd0, cd1, &accd0, ones);
        short8 af1 = make_pfrag(cm1, ssi1, cd0, cd1, &accd1, ones);

        const __hip_bfloat16* hbt = hb + (size_t)t * 8 * 512;
#pragma unroll
        for (int f = 0; f < 8; f++) {
            short8 bf = *(const short8*)(hbt + f * 512);
            acc0[f] = __builtin_amdgcn_mfma_f32_16x16x32_bf16(af0, bf, acc0[f], 0, 0, 0);
            acc1[f] = __builtin_amdgcn_mfma_f32_16x16x32_bf16(af1, bf, acc1[f], 0, 0, 0);
        }
    }

    // epilogue: C/D layout col(dim-part)=lm, row=lq*4+r
    float* nb = num + ((size_t)jh * NN + i0) * DOUT;
#pragma unroll
    for (int f = 0; f < 8; f++)
#pragma unroll
        for (int r = 0; r < 4; r++) {
            nb[(size_t)(lq * 4 + r) * DOUT + f * 16 + lm] = acc0[f][r];
            nb[(size_t)(16 + lq * 4 + r) * DOUT + f * 16 + lm] = acc1[f][r];
        }
    if (lm == 0) {
#pragma unroll
        for (int r = 0; r < 4; r++) {
            lpart[(size_t)jh * NN + i0 + lq * 4 + r] = accd0[r];
            lpart[(size_t)jh * NN + i0 + 16 + lq * 4 + r] = accd1[r];
        }
    }
}

// ---------------- kernel 4: combine partials, divide ----------------
__global__ void gat_combine(const float* __restrict__ num, const float* __restrict__ lpart,
                            float* __restrict__ out, int jsplit) {
    int gid = blockIdx.x * blockDim.x + threadIdx.x;  // 262144 threads, one float4 each
    int idx = gid * 4;
    int i = idx >> 7;
    float den = 0.f;
    for (int s = 0; s < jsplit; s++) den += lpart[(size_t)s * NN + i];
    float inv = 1.0f / den;
    float4 o = make_float4(0.f, 0.f, 0.f, 0.f);
    for (int s = 0; s < jsplit; s++) {
        float4 n = *(const float4*)&num[(size_t)s * NN * DOUT + idx];
        o.x += n.x; o.y += n.y; o.z += n.z; o.w += n.w;
    }
    o.x *= inv; o.y *= inv; o.z *= inv; o.w *= inv;
    *(float4*)&out[idx] = o;
}

extern "C" void kernel_launch(void* const* d_in, const int* in_sizes, int n_in,
                              void* d_out, int out_size, void* d_ws, size_t ws_size,
                              hipStream_t stream) {
    const float* x  = (const float*)d_in[0];
    const int* adj  = (const int*)d_in[1];
    const float* W  = (const float*)d_in[2];
    const float* bW = (const float*)d_in[3];
    const float* a1 = (const float*)d_in[4];
    const float* a2 = (const float*)d_in[5];
    const float* ba = (const float*)d_in[6];
    float* out = (float*)d_out;

    char* ws = (char*)d_ws;
    __hip_bfloat16* hbB  = (__hip_bfloat16*)ws;                    // 2 MB   frag-tile layout
    __hip_bfloat16* WT   = (__hip_bfloat16*)(ws + 2097152);        // 64 KB
    float* s_src         = (float*)(ws + 2162688);                 // 32 KB (pre-scaled by log2e)
    float* s_dst         = (float*)(ws + 2195456);                 // 32 KB (pre-scaled by log2e)
    float* lpart         = (float*)(ws + 2228224);                 // 512 KB [<=16][8192]
    unsigned char* mask  = (unsigned char*)(ws + 2752512);         // 8 MB   permuted
    float* num           = (float*)(ws + 11141120);                // jsplit*4 MB

    int jsplit = (ws_size >= 11141120 + (size_t)16 * NN * DOUT * 4) ? 16 : 8;

    // build_mask first: keeps gat_h's outputs (hbB/s_dst) L2-warm for gat_attn.
    if (jsplit == 16) build_mask<16><<<32768, 256, 0, stream>>>(adj, mask);
    else              build_mask<32><<<32768, 256, 0, stream>>>(adj, mask);
    prep_wt<<<128, 256, 0, stream>>>(W, WT);
    gat_h<<<256, 256, 0, stream>>>(x, WT, bW, a1, a2, hbB, s_src, s_dst);
    if (jsplit == 16)
        gat_attn<16><<<1024, 256, 0, stream>>>(mask, s_src, s_dst, ba, hbB, num, lpart);
    else
        gat_attn<32><<<512, 256, 0, stream>>>(mask, s_src, s_dst, ba, hbB, num, lpart);
    gat_combine<<<1024, 256, 0, stream>>>(num, lpart, out, jsplit);
}